// Round 7
// baseline (209.299 us; speedup 1.0000x reference)
//
#include <hip/hip_runtime.h>
#include <hip/hip_bf16.h>

// EdgeEmbedder fused kernels for MI355X (gfx950). Round 11.
//   R10 post-mortem: 8-wave/512-thread (16 waves/CU) = 199.6us vs R7 197.3
//   -> NEUTRAL. edge_main is NOT TLP/latency-bound (gl_lds prefetch already
//   covers latency at 2 waves/SIMD). Remaining regime: streaming-store +
//   fixed overhead. Reverting to R7's exact 256-thread structure (best).
//   R11 single-variable A/B: epilogue stores -> __builtin_nontemporal_store.
//   Mechanism: out = 134MB f32, written once, never re-read; plain stores
//   allocate in L2 and evict the gl_lds-hot tables (p_bf/relT/W1b, re-read
//   by every block every tile). nt keeps tables L2-resident. (R6 bundled nt
//   with setprio and regressed; setprio was the identified culprit -- this
//   isolates nt on the best base.)

typedef __attribute__((ext_vector_type(8))) short v8s;   // 8 x bf16 fragment
typedef __attribute__((ext_vector_type(4))) float v4f;   // 4 x f32 accumulator

#define PI_F 3.14159265358979323846f

__device__ __forceinline__ unsigned short f2bu(float x) {
    __hip_bfloat16 h = __float2bfloat16(x);
    return *reinterpret_cast<unsigned short*>(&h);
}
__device__ __forceinline__ float bu2f(unsigned short u) {
    union { unsigned int i; float f; } c; c.i = ((unsigned int)u) << 16;
    return c.f;
}
// width-16 global->LDS DMA. LDS dest is wave-uniform base + lane*16 (HW);
// per-lane global src carries the swizzle.
__device__ __forceinline__ void gld16(const void* g, void* l) {
    __builtin_amdgcn_global_load_lds(
        (__attribute__((address_space(1))) void*)(void*)(g),
        (__attribute__((address_space(3))) void*)(l), 16, 0, 0);
}

// ---------------------------------------------------------------------------
// Precompute: blocks 0..63 -> p rows; 64..319 -> relpos rows; 320..343 ->
// W1/W2 bf16 cast. (unchanged)
// ---------------------------------------------------------------------------
__global__ __launch_bounds__(256) void precompute_kernel(
    const float* __restrict__ s, const float* __restrict__ W_sp,
    const float* __restrict__ b_sp, const float* __restrict__ W_rp,
    const float* __restrict__ b_rp, const float* __restrict__ W1,
    const float* __restrict__ W2,
    __hip_bfloat16* __restrict__ p_bf, __hip_bfloat16* __restrict__ relT,
    __hip_bfloat16* __restrict__ W1b, __hip_bfloat16* __restrict__ W2b)
{
    const int b = blockIdx.x;
    const int tid = threadIdx.x;
    __shared__ float lds[128 * 65 + 8 * 256];

    if (b < 64) {
        float* Wt   = lds;               // [128][65] transposed slice of W_sp
        float* srow = lds + 128 * 65;    // [8][256]
        const int row0 = b * 8;
        const int f  = tid & 63;
        const int rh = tid >> 6;
        #pragma unroll
        for (int k = 0; k < 8; k++) {
            const int idx = tid + 256 * k;
            const int r = idx >> 8, d = idx & 255;
            srow[r * 256 + d] = s[(row0 + r) * 256 + d];
        }
        float acc0 = b_sp[f];
        float acc1 = acc0;
        for (int pass = 0; pass < 2; pass++) {
            __syncthreads();
            #pragma unroll
            for (int k = 0; k < 32; k++) {
                const int idx = tid + 256 * k;
                const int fs = idx >> 7, ds = idx & 127;
                Wt[ds * 65 + fs] = W_sp[fs * 256 + pass * 128 + ds];
            }
            __syncthreads();
            #pragma unroll 4
            for (int d = 0; d < 128; d++) {
                const float w = Wt[d * 65 + f];
                acc0 += srow[rh * 256 + pass * 128 + d] * w;
                acc1 += srow[(rh + 4) * 256 + pass * 128 + d] * w;
            }
        }
        p_bf[(row0 + rh) * 64 + f]     = __float2bfloat16(acc0);
        p_bf[(row0 + rh + 4) * 64 + f] = __float2bfloat16(acc1);
    } else if (b < 320) {
        float* WrT  = lds;               // [64][65] transposed W_rp
        float* femb = lds + 64 * 65;     // [4][64]
        const int r0 = (b - 64) * 4;
        #pragma unroll
        for (int k = 0; k < 16; k++) {
            const int idx = tid + 256 * k;
            const int g = idx >> 6, ff = idx & 63;
            WrT[ff * 65 + g] = W_rp[g * 64 + ff];
        }
        {
            const int r = tid >> 6, c = tid & 63;
            const float rel = (float)(r0 + r - 511);
            const int K = c & 31;
            // 2056^(-K/32) = exp2(-K * log2(2056)/32); log2(2056)/32 = 0.34392577
            const float freq_inv = exp2f(-(float)K * 0.34392577f);
            const float ang = rel * PI_F * freq_inv;
            femb[r * 64 + c] = (c < 32) ? sinf(ang) : cosf(ang);
        }
        __syncthreads();
        const int g = tid & 63, r = tid >> 6;
        float acc = b_rp[g];
        #pragma unroll
        for (int ff = 0; ff < 64; ff++) acc += femb[r * 64 + ff] * WrT[ff * 65 + g];
        relT[(r0 + r) * 64 + g] = __float2bfloat16(acc);
    } else {
        #pragma unroll
        for (int k = 0; k < 2; k++) {
            const int idx4 = (b - 320) * 512 + k * 256 + tid;
            const int e = idx4 * 4;
            const float4 v = (e < 32768) ? *(const float4*)&W1[e]
                                         : *(const float4*)&W2[e - 32768];
            __hip_bfloat16* dst = (e < 32768) ? (W1b + e) : (W2b + (e - 32768));
            dst[0] = __float2bfloat16(v.x);
            dst[1] = __float2bfloat16(v.y);
            dst[2] = __float2bfloat16(v.z);
            dst[3] = __float2bfloat16(v.w);
        }
    }
}

// ---------------------------------------------------------------------------
// Main kernel (R7 structure). Block = one i (512 blocks, 256 threads,
// 2 blocks/CU), 8 j-tiles of 64. Wave wv owns output cols [32wv, 32wv+32).
// LDS map (57344B):
//   slot s (s=0,1) @ s*16384 : pj plane [0,8K) | rel plane [8K,16K)
//   rbf/pre plane  @ 32768   : 64 rows x 128B, f: rbf 0..43, pre 44..63
//   H              @ 40960   : 64 rows x 256B (also prologue scratch)
// Swizzle: within a 128B row, 16B chunk c stored at chunk (c ^ (row&7)).
// Barriers (T4 counted): MID lgkmcnt(0); END vmcnt(8) lgkmcnt(0).
// ---------------------------------------------------------------------------
__global__ __launch_bounds__(256, 2) void edge_main(
    const float* __restrict__ t3, const float* __restrict__ sc3,
    const float* __restrict__ pre, const float* __restrict__ b1,
    const float* __restrict__ b2,
    const __hip_bfloat16* __restrict__ p_bf, const __hip_bfloat16* __restrict__ relT,
    const __hip_bfloat16* __restrict__ W1b, const __hip_bfloat16* __restrict__ W2b,
    float* __restrict__ out)
{
    __shared__ char smem[57344];

    const int tid  = threadIdx.x;
    const int i    = blockIdx.x;
    const int wv   = tid >> 6;
    const int lane = tid & 63;
    const int l16  = lane & 15;
    const int quad = lane >> 4;
    const int cbase = wv * 32;
    const int xr = l16 & 7;

    // ---- weights -> registers (once per block) ----
    v8s w1f[2][6];
    v8s w2f[2][4];
    {
        const __hip_bfloat16* a = W1b + (cbase + l16) * 256 + 64 + quad * 8;
        #pragma unroll
        for (int mt = 0; mt < 2; mt++)
            #pragma unroll
            for (int kt = 0; kt < 6; kt++)
                w1f[mt][kt] = *(const v8s*)(a + mt * 16 * 256 + kt * 32);
        const __hip_bfloat16* a2 = W2b + (cbase + l16) * 128 + quad * 8;
        #pragma unroll
        for (int mt = 0; mt < 2; mt++)
            #pragma unroll
            for (int kt = 0; kt < 4; kt++)
                w2f[mt][kt] = *(const v8s*)(a2 + mt * 16 * 128 + kt * 32);
    }
    const float4 bz0 = *(const float4*)&b2[cbase + quad * 4];
    const float4 bz1 = *(const float4*)&b2[cbase + 16 + quad * 4];

    const float tix = t3[i * 3], tiy = t3[i * 3 + 1], tiz = t3[i * 3 + 2];
    const float six = sc3[i * 3], siy = sc3[i * 3 + 1], siz = sc3[i * 3 + 2];

    // staging thread maps
    const int rp0 = tid / 5, qp0 = tid % 5;                  // pre slot 0
    const int rp1 = (tid + 256) / 5, qp1 = (tid + 256) % 5;  // pre slot 1 (tid<64)
    const int rr = tid >> 2, fo = (tid & 3) * 11;            // rbf row, feature base
    const int g8r = lane >> 3, g8c = lane & 7;               // gl_lds chunk map

    float4 s_prA, s_prB;
    float s_dt, s_ds;

    char* const rbfp = smem + 32768;
    char* const Hb   = smem + 40960;

    // pj + rel planes for tile j0n -> slot, via gl_lds with pre-swizzled src.
    // LDS chunk q holds global chunk (q&7)^(row&7) of row q>>3.
    // gl_lds issued BEFORE stage_regs loads (older in vmcnt FIFO) so the
    // implicit wait on pre-loads in build_rbfpre retires them too.
    auto stage_glds = [&](int j0n, char* slot) {
        #pragma unroll
        for (int c = 0; c < 2; c++) {
            const int r  = (wv * 2 + c) * 8 + g8r;
            const int cs = g8c ^ (r & 7);
            gld16(p_bf + (j0n + r) * 64 + cs * 8,
                  slot + (wv * 2 + c) * 1024);
            gld16(relT + (i - (j0n + r) + 511) * 64 + cs * 8,
                  slot + 8192 + (wv * 2 + c) * 1024);
        }
    };

    auto stage_regs = [&](int j0n) {
        s_prA = *(const float4*)&pre[((size_t)i * 512 + j0n + rp0) * 20 + qp0 * 4];
        if (tid < 64)
            s_prB = *(const float4*)&pre[((size_t)i * 512 + j0n + rp1) * 20 + qp1 * 4];
        const int j = j0n + rr;
        const float dx = tix - t3[j * 3], dy = tiy - t3[j * 3 + 1], dz = tiz - t3[j * 3 + 2];
        s_dt = sqrtf(dx * dx + dy * dy + dz * dz);
        const float ex = six - sc3[j * 3], ey = siy - sc3[j * 3 + 1], ez = siz - sc3[j * 3 + 2];
        s_ds = sqrtf(ex * ex + ey * ey + ez * ez);
    };

    auto build_rbfpre = [&]() {
        union { unsigned short u2[4]; uint2 u; } pk;
        {   // pre -> cols 44..63
            const int f0 = 44 + qp0 * 4;
            pk.u2[0] = f2bu(s_prA.x); pk.u2[1] = f2bu(s_prA.y);
            pk.u2[2] = f2bu(s_prA.z); pk.u2[3] = f2bu(s_prA.w);
            *(uint2*)(rbfp + rp0 * 128 + (((f0 >> 3) ^ (rp0 & 7)) << 4) + (f0 & 7) * 2) = pk.u;
            if (tid < 64) {
                const int f1 = 44 + qp1 * 4;
                pk.u2[0] = f2bu(s_prB.x); pk.u2[1] = f2bu(s_prB.y);
                pk.u2[2] = f2bu(s_prB.z); pk.u2[3] = f2bu(s_prB.w);
                *(uint2*)(rbfp + rp1 * 128 + (((f1 >> 3) ^ (rp1 & 7)) << 4) + (f1 & 7) * 2) = pk.u;
            }
        }
        {   // RBF -> cols 0..43
            const int rxr = rr & 7;
            char* rowp = rbfp + rr * 128;
            #pragma unroll
            for (int q = 0; q < 11; q++) {
                const int f = fo + q;
                const float d = (f < 22) ? s_dt : s_ds;
                const int m = (f < 22) ? f : f - 22;
                const float x = (d - (float)m * (20.0f / 21.0f)) * 1.1f;
                *(unsigned short*)(rowp + (((f >> 3) ^ rxr) << 4) + (f & 7) * 2)
                    = f2bu(__expf(-x * x));
            }
        }
    };

    // ---- prologue: tile-0 staging + fused bias1 ----
    float* pshare  = (float*)(smem + 40960);        // H region is free pre-loop
    float* biasLds = (float*)(smem + 40960 + 256);
    if (tid < 64) pshare[tid] = bu2f(((const unsigned short*)p_bf)[i * 64 + tid]);
    stage_glds(0, smem);
    stage_regs(0);
    __syncthreads();   // pshare visible (gl_lds tile0 also drains here)

    float4 bo0, bo1;
    {   // bias1[i][col] = b1[col] + sum_{f<64} p[i][f] * W1b[col][f]
        const int colL = lane & 31;
        const int h = lane >> 5;
        const unsigned short* wrow =
            (const unsigned short*)W1b + (cbase + colL) * 256 + h * 32;
        float acc = 0.f;
        #pragma unroll
        for (int k = 0; k < 4; k++) {
            const v8s w8 = *(const v8s*)(wrow + k * 8);
            #pragma unroll
            for (int e = 0; e < 8; e++)
                acc += pshare[h * 32 + k * 8 + e] * bu2f((unsigned short)w8[e]);
        }
        acc += __shfl_xor(acc, 32);                 // combine halves (f<32 / f>=32)
        biasLds[wv * 32 + colL] = b1[cbase + colL] + acc;   // wave-local region
        bo0 = *(const float4*)&biasLds[wv * 32 + quad * 4];
        bo1 = *(const float4*)&biasLds[wv * 32 + 16 + quad * 4];
    }
    build_rbfpre();
    __syncthreads();   // rbf plane(0) ready; H region now owned by loop

    const size_t orow0 = (size_t)i * 512;

    #pragma unroll 1
    for (int s = 0; s < 8; s++) {
        char* slot  = smem + (s & 1) * 16384;
        char* slotN = smem + ((s + 1) & 1) * 16384;
        if (s < 7) { stage_glds((s + 1) * 64, slotN); stage_regs((s + 1) * 64); }

        // ---- Layer 1: K=192, weights in regs ----
        v4f acc[2][4];
        #pragma unroll
        for (int mt = 0; mt < 2; mt++)
            #pragma unroll
            for (int nt = 0; nt < 4; nt++) acc[mt][nt] = (v4f){0.f, 0.f, 0.f, 0.f};

        #pragma unroll
        for (int kt = 0; kt < 6; kt++) {
            // kt 0,1 -> pj plane; 2,3 -> rel plane; 4,5 -> rbf/pre plane
            const char* P = (kt < 2) ? slot : (kt < 4) ? (slot + 8192) : rbfp;
            const int gg = (kt & 1) * 4 + quad;
            const int po = ((gg ^ xr) << 4);
            const v8s t0  = *(const v8s*)(P + (l16     ) * 128 + po);
            const v8s t1  = *(const v8s*)(P + (l16 + 16) * 128 + po);
            const v8s t2  = *(const v8s*)(P + (l16 + 32) * 128 + po);
            const v8s t3v = *(const v8s*)(P + (l16 + 48) * 128 + po);
            acc[0][0] = __builtin_amdgcn_mfma_f32_16x16x32_bf16(w1f[0][kt], t0,  acc[0][0], 0, 0, 0);
            acc[0][1] = __builtin_amdgcn_mfma_f32_16x16x32_bf16(w1f[0][kt], t1,  acc[0][1], 0, 0, 0);
            acc[0][2] = __builtin_amdgcn_mfma_f32_16x16x32_bf16(w1f[0][kt], t2,  acc[0][2], 0, 0, 0);
            acc[0][3] = __builtin_amdgcn_mfma_f32_16x16x32_bf16(w1f[0][kt], t3v, acc[0][3], 0, 0, 0);
            acc[1][0] = __builtin_amdgcn_mfma_f32_16x16x32_bf16(w1f[1][kt], t0,  acc[1][0], 0, 0, 0);
            acc[1][1] = __builtin_amdgcn_mfma_f32_16x16x32_bf16(w1f[1][kt], t1,  acc[1][1], 0, 0, 0);
            acc[1][2] = __builtin_amdgcn_mfma_f32_16x16x32_bf16(w1f[1][kt], t2,  acc[1][2], 0, 0, 0);
            acc[1][3] = __builtin_amdgcn_mfma_f32_16x16x32_bf16(w1f[1][kt], t3v, acc[1][3], 0, 0, 0);
        }

        // ---- H = relu(acc + bias1_i) -> H plane ----
        #pragma unroll
        for (int mt = 0; mt < 2; mt++) {
            const float4 bv = mt ? bo1 : bo0;
            const int col = cbase + mt * 16 + quad * 4;
            const int cch = col >> 3;
            const int boff = (col & 7) * 2;
            #pragma unroll
            for (int nt = 0; nt < 4; nt++) {
                const int row = nt * 16 + l16;
                union { unsigned short u2[4]; uint2 u; } pk;
                pk.u2[0] = f2bu(fmaxf(acc[mt][nt][0] + bv.x, 0.f));
                pk.u2[1] = f2bu(fmaxf(acc[mt][nt][1] + bv.y, 0.f));
                pk.u2[2] = f2bu(fmaxf(acc[mt][nt][2] + bv.z, 0.f));
                pk.u2[3] = f2bu(fmaxf(acc[mt][nt][3] + bv.w, 0.f));
                *(uint2*)(Hb + row * 256 + ((cch ^ (row & 7)) << 4) + boff) = pk.u;
            }
        }
        // MID barrier: H (LDS) complete; L2 phase has NO vmem dependency ->
        // lgkmcnt(0) only. Pre-loads + gl_lds for t+1 stay in flight.
        asm volatile("s_waitcnt lgkmcnt(0)" ::: "memory");
        __builtin_amdgcn_s_barrier();
        __builtin_amdgcn_sched_barrier(0);

        // ---- Layer 2: K=128 from H ----
        v4f acc2[2][4];
        #pragma unroll
        for (int mt = 0; mt < 2; mt++)
            #pragma unroll
            for (int nt = 0; nt < 4; nt++) acc2[mt][nt] = (v4f){0.f, 0.f, 0.f, 0.f};

        #pragma unroll
        for (int kt = 0; kt < 4; kt++) {
            const int g = kt * 4 + quad;
            const int po = ((g ^ xr) << 4);
            const v8s t0  = *(const v8s*)(Hb + (l16     ) * 256 + po);
            const v8s t1  = *(const v8s*)(Hb + (l16 + 16) * 256 + po);
            const v8s t2  = *(const v8s*)(Hb + (l16 + 32) * 256 + po);
            const v8s t3v = *(const v8s*)(Hb + (l16 + 48) * 256 + po);
            acc2[0][0] = __builtin_amdgcn_mfma_f32_16x16x32_bf16(w2f[0][kt], t0,  acc2[0][0], 0, 0, 0);
            acc2[0][1] = __builtin_amdgcn_mfma_f32_16x16x32_bf16(w2f[0][kt], t1,  acc2[0][1], 0, 0, 0);
            acc2[0][2] = __builtin_amdgcn_mfma_f32_16x16x32_bf16(w2f[0][kt], t2,  acc2[0][2], 0, 0, 0);
            acc2[0][3] = __builtin_amdgcn_mfma_f32_16x16x32_bf16(w2f[0][kt], t3v, acc2[0][3], 0, 0, 0);
            acc2[1][0] = __builtin_amdgcn_mfma_f32_16x16x32_bf16(w2f[1][kt], t0,  acc2[1][0], 0, 0, 0);
            acc2[1][1] = __builtin_amdgcn_mfma_f32_16x16x32_bf16(w2f[1][kt], t1,  acc2[1][1], 0, 0, 0);
            acc2[1][2] = __builtin_amdgcn_mfma_f32_16x16x32_bf16(w2f[1][kt], t2,  acc2[1][2], 0, 0, 0);
            acc2[1][3] = __builtin_amdgcn_mfma_f32_16x16x32_bf16(w2f[1][kt], t3v, acc2[1][3], 0, 0, 0);
        }

        // rbf/pre plane for t+1: only L1 reads it, and all L1 reads finished
        // at the mid-barrier -> safe to overwrite here (single-buffered).
        // The implicit vmcnt wait on s_pr*/s_dt here also retires the older
        // gl_lds ops (in-order FIFO) -> slotN guaranteed ready by END.
        if (s < 7) build_rbfpre();

        // ---- epilogue: +b2, NONTEMPORAL float4 stores (134MB streamed,
        //      never re-read; keep L2 for the gl_lds tables) ----
        #pragma unroll
        for (int mt = 0; mt < 2; mt++) {
            const float4 bv = mt ? bz1 : bz0;
            const int col = cbase + mt * 16 + quad * 4;
            #pragma unroll
            for (int nt = 0; nt < 4; nt++) {
                const size_t row = orow0 + s * 64 + nt * 16 + l16;
                v4f o;
                o[0] = acc2[mt][nt][0] + bv.x;
                o[1] = acc2[mt][nt][1] + bv.y;
                o[2] = acc2[mt][nt][2] + bv.z;
                o[3] = acc2[mt][nt][3] + bv.w;
                __builtin_nontemporal_store(o, (v4f*)(out + row * 128 + col));
            }
        }

        // END barrier: rbf(t+1) LDS writes visible (lgkm 0); the 8 epilogue
        // stores may stay in flight (vmcnt 8). gl_lds(t+1) already retired.
        asm volatile("s_waitcnt vmcnt(8) lgkmcnt(0)" ::: "memory");
        __builtin_amdgcn_s_barrier();
        __builtin_amdgcn_sched_barrier(0);
    }
}

// ---------------------------------------------------------------------------
extern "C" void kernel_launch(void* const* d_in, const int* in_sizes, int n_in,
                              void* d_out, int out_size, void* d_ws, size_t ws_size,
                              hipStream_t stream) {
    const float* s    = (const float*)d_in[0];
    const float* t3   = (const float*)d_in[1];
    const float* sc3  = (const float*)d_in[2];
    const float* pre  = (const float*)d_in[3];
    // d_in[4] = p_mask (all-ones, never applied in reference math)
    const float* W_sp = (const float*)d_in[5];
    const float* b_sp = (const float*)d_in[6];
    const float* W_rp = (const float*)d_in[7];
    const float* b_rp = (const float*)d_in[8];
    const float* W1   = (const float*)d_in[9];
    const float* b1   = (const float*)d_in[10];
    const float* W2   = (const float*)d_in[11];
    const float* b2   = (const float*)d_in[12];
    float* out = (float*)d_out;

    char* ws = (char*)d_ws;
    __hip_bfloat16* p_bf = (__hip_bfloat16*)(ws);                   // 64 KiB @0
    __hip_bfloat16* relT = (__hip_bfloat16*)(ws + 65536);           // 128 KiB
    __hip_bfloat16* W1b  = (__hip_bfloat16*)(ws + 196608);          // 64 KiB
    __hip_bfloat16* W2b  = (__hip_bfloat16*)(ws + 262144);          // 32 KiB

    precompute_kernel<<<344, 256, 0, stream>>>(s, W_sp, b_sp, W_rp, b_rp, W1, W2,
                                               p_bf, relT, W1b, W2b);
    edge_main<<<512, 256, 0, stream>>>(t3, sc3, pre, b1, b2,
                                       p_bf, relT, W1b, W2b, out);
}

// Round 8
// 195.062 us; speedup vs baseline: 1.0730x; 1.0730x over previous
//
#include <hip/hip_runtime.h>
#include <hip/hip_bf16.h>

// EdgeEmbedder fused kernels for MI355X (gfx950). Round 12 = byte-exact R7
// revert (session-best, 197.3us verified).
//   Session A/B ledger (hardware-verified):
//     R4 baseline 3-launch reg-staged ............ 203.8
//     R6 +bias1fuse+gl_lds+setprio+nt ............ 209.8 (package regression)
//     R7 bias1fuse+gl_lds+counted-waitcnt ........ 197.3  <-- BEST (this file)
//     R8 direct-global B, 1 barrier/tile ......... 211.2 (prefetch load-bearing)
//     R10 8-wave same schedule ................... 199.6 (not TLP-bound)
//     R11 R7+nt-stores ........................... 209.3 (nt isolated: -12)
//   Confirmed levers: fewer launches (bias1 fusion) + counted-waitcnt
//   barriers (MID lgkmcnt-only, END vmcnt(8)) -- both in this kernel.
//   Confirmed regressors: setprio (lockstep waves), nt-stores, removing the
//   gl_lds tile-ahead prefetch, single-barrier pipelining at 2 waves/SIMD.

typedef __attribute__((ext_vector_type(8))) short v8s;   // 8 x bf16 fragment
typedef __attribute__((ext_vector_type(4))) float v4f;   // 4 x f32 accumulator

#define PI_F 3.14159265358979323846f

__device__ __forceinline__ unsigned short f2bu(float x) {
    __hip_bfloat16 h = __float2bfloat16(x);
    return *reinterpret_cast<unsigned short*>(&h);
}
__device__ __forceinline__ float bu2f(unsigned short u) {
    union { unsigned int i; float f; } c; c.i = ((unsigned int)u) << 16;
    return c.f;
}
// width-16 global->LDS DMA. LDS dest is wave-uniform base + lane*16 (HW);
// per-lane global src carries the swizzle.
__device__ __forceinline__ void gld16(const void* g, void* l) {
    __builtin_amdgcn_global_load_lds(
        (__attribute__((address_space(1))) void*)(void*)(g),
        (__attribute__((address_space(3))) void*)(l), 16, 0, 0);
}

// ---------------------------------------------------------------------------
// Precompute: blocks 0..63 -> p rows; 64..319 -> relpos rows; 320..343 ->
// W1/W2 bf16 cast.
// ---------------------------------------------------------------------------
__global__ __launch_bounds__(256) void precompute_kernel(
    const float* __restrict__ s, const float* __restrict__ W_sp,
    const float* __restrict__ b_sp, const float* __restrict__ W_rp,
    const float* __restrict__ b_rp, const float* __restrict__ W1,
    const float* __restrict__ W2,
    __hip_bfloat16* __restrict__ p_bf, __hip_bfloat16* __restrict__ relT,
    __hip_bfloat16* __restrict__ W1b, __hip_bfloat16* __restrict__ W2b)
{
    const int b = blockIdx.x;
    const int tid = threadIdx.x;
    __shared__ float lds[128 * 65 + 8 * 256];

    if (b < 64) {
        float* Wt   = lds;               // [128][65] transposed slice of W_sp
        float* srow = lds + 128 * 65;    // [8][256]
        const int row0 = b * 8;
        const int f  = tid & 63;
        const int rh = tid >> 6;
        #pragma unroll
        for (int k = 0; k < 8; k++) {
            const int idx = tid + 256 * k;
            const int r = idx >> 8, d = idx & 255;
            srow[r * 256 + d] = s[(row0 + r) * 256 + d];
        }
        float acc0 = b_sp[f];
        float acc1 = acc0;
        for (int pass = 0; pass < 2; pass++) {
            __syncthreads();
            #pragma unroll
            for (int k = 0; k < 32; k++) {
                const int idx = tid + 256 * k;
                const int fs = idx >> 7, ds = idx & 127;
                Wt[ds * 65 + fs] = W_sp[fs * 256 + pass * 128 + ds];
            }
            __syncthreads();
            #pragma unroll 4
            for (int d = 0; d < 128; d++) {
                const float w = Wt[d * 65 + f];
                acc0 += srow[rh * 256 + pass * 128 + d] * w;
                acc1 += srow[(rh + 4) * 256 + pass * 128 + d] * w;
            }
        }
        p_bf[(row0 + rh) * 64 + f]     = __float2bfloat16(acc0);
        p_bf[(row0 + rh + 4) * 64 + f] = __float2bfloat16(acc1);
    } else if (b < 320) {
        float* WrT  = lds;               // [64][65] transposed W_rp
        float* femb = lds + 64 * 65;     // [4][64]
        const int r0 = (b - 64) * 4;
        #pragma unroll
        for (int k = 0; k < 16; k++) {
            const int idx = tid + 256 * k;
            const int g = idx >> 6, ff = idx & 63;
            WrT[ff * 65 + g] = W_rp[g * 64 + ff];
        }
        {
            const int r = tid >> 6, c = tid & 63;
            const float rel = (float)(r0 + r - 511);
            const int K = c & 31;
            // 2056^(-K/32) = exp2(-K * log2(2056)/32); log2(2056)/32 = 0.34392577
            const float freq_inv = exp2f(-(float)K * 0.34392577f);
            const float ang = rel * PI_F * freq_inv;
            femb[r * 64 + c] = (c < 32) ? sinf(ang) : cosf(ang);
        }
        __syncthreads();
        const int g = tid & 63, r = tid >> 6;
        float acc = b_rp[g];
        #pragma unroll
        for (int ff = 0; ff < 64; ff++) acc += femb[r * 64 + ff] * WrT[ff * 65 + g];
        relT[(r0 + r) * 64 + g] = __float2bfloat16(acc);
    } else {
        #pragma unroll
        for (int k = 0; k < 2; k++) {
            const int idx4 = (b - 320) * 512 + k * 256 + tid;
            const int e = idx4 * 4;
            const float4 v = (e < 32768) ? *(const float4*)&W1[e]
                                         : *(const float4*)&W2[e - 32768];
            __hip_bfloat16* dst = (e < 32768) ? (W1b + e) : (W2b + (e - 32768));
            dst[0] = __float2bfloat16(v.x);
            dst[1] = __float2bfloat16(v.y);
            dst[2] = __float2bfloat16(v.z);
            dst[3] = __float2bfloat16(v.w);
        }
    }
}

// ---------------------------------------------------------------------------
// Main persistent kernel. Block = one i (512 blocks, 2/CU), 8 j-tiles of 64.
// Wave wv owns output cols [32wv, 32wv+32). A=weight frag (regs), B=tile frag.
// LDS map (57344B total):
//   slot s (s=0,1) @ s*16384 : pj plane [0,8K) | rel plane [8K,16K)
//   rbf/pre plane  @ 32768   : 64 rows x 128B, f in [0,64): rbf 0..43, pre 44..63
//   H              @ 40960   : 64 rows x 256B (also prologue scratch)
// Swizzle: within a 128B row, 16B chunk c stored at chunk (c ^ (row&7)).
// pj/rel planes filled by global_load_lds with the XOR applied to the SOURCE.
// Barrier discipline (T4):
//   MID: lgkmcnt(0) + s_barrier            (no vmem dep in L2 phase)
//   END: vmcnt(8) lgkmcnt(0) + s_barrier   (epilogue stores stay in flight;
//        gl_lds already retired by pre-load implicit wait in build_rbfpre)
// ---------------------------------------------------------------------------
__global__ __launch_bounds__(256, 2) void edge_main(
    const float* __restrict__ t3, const float* __restrict__ sc3,
    const float* __restrict__ pre, const float* __restrict__ b1,
    const float* __restrict__ b2,
    const __hip_bfloat16* __restrict__ p_bf, const __hip_bfloat16* __restrict__ relT,
    const __hip_bfloat16* __restrict__ W1b, const __hip_bfloat16* __restrict__ W2b,
    float* __restrict__ out)
{
    __shared__ char smem[57344];

    const int tid  = threadIdx.x;
    const int i    = blockIdx.x;
    const int wv   = tid >> 6;
    const int lane = tid & 63;
    const int l16  = lane & 15;
    const int quad = lane >> 4;
    const int cbase = wv * 32;
    const int xr = l16 & 7;

    // ---- weights -> registers (once per block) ----
    v8s w1f[2][6];
    v8s w2f[2][4];
    {
        const __hip_bfloat16* a = W1b + (cbase + l16) * 256 + 64 + quad * 8;
        #pragma unroll
        for (int mt = 0; mt < 2; mt++)
            #pragma unroll
            for (int kt = 0; kt < 6; kt++)
                w1f[mt][kt] = *(const v8s*)(a + mt * 16 * 256 + kt * 32);
        const __hip_bfloat16* a2 = W2b + (cbase + l16) * 128 + quad * 8;
        #pragma unroll
        for (int mt = 0; mt < 2; mt++)
            #pragma unroll
            for (int kt = 0; kt < 4; kt++)
                w2f[mt][kt] = *(const v8s*)(a2 + mt * 16 * 128 + kt * 32);
    }
    const float4 bz0 = *(const float4*)&b2[cbase + quad * 4];
    const float4 bz1 = *(const float4*)&b2[cbase + 16 + quad * 4];

    const float tix = t3[i * 3], tiy = t3[i * 3 + 1], tiz = t3[i * 3 + 2];
    const float six = sc3[i * 3], siy = sc3[i * 3 + 1], siz = sc3[i * 3 + 2];

    // staging thread maps
    const int rp0 = tid / 5, qp0 = tid % 5;                  // pre slot 0
    const int rp1 = (tid + 256) / 5, qp1 = (tid + 256) % 5;  // pre slot 1 (tid<64)
    const int rr = tid >> 2, fo = (tid & 3) * 11;            // rbf row, feature base
    const int g8r = lane >> 3, g8c = lane & 7;               // gl_lds chunk map

    float4 s_prA, s_prB;
    float s_dt, s_ds;

    char* const rbfp = smem + 32768;
    char* const Hb   = smem + 40960;

    // pj + rel planes for tile j0n -> slot, via gl_lds with pre-swizzled src.
    // LDS chunk q holds global chunk (q&7)^(row&7) of row q>>3.
    // NOTE: gl_lds issued BEFORE stage_regs loads (older in vmcnt FIFO) so
    // the implicit wait on pre-loads in build_rbfpre retires them too.
    auto stage_glds = [&](int j0n, char* slot) {
        #pragma unroll
        for (int c = 0; c < 2; c++) {
            const int r  = (wv * 2 + c) * 8 + g8r;
            const int cs = g8c ^ (r & 7);
            gld16(p_bf + (j0n + r) * 64 + cs * 8,
                  slot + (wv * 2 + c) * 1024);
            gld16(relT + (i - (j0n + r) + 511) * 64 + cs * 8,
                  slot + 8192 + (wv * 2 + c) * 1024);
        }
    };

    auto stage_regs = [&](int j0n) {
        s_prA = *(const float4*)&pre[((size_t)i * 512 + j0n + rp0) * 20 + qp0 * 4];
        if (tid < 64)
            s_prB = *(const float4*)&pre[((size_t)i * 512 + j0n + rp1) * 20 + qp1 * 4];
        const int j = j0n + rr;
        const float dx = tix - t3[j * 3], dy = tiy - t3[j * 3 + 1], dz = tiz - t3[j * 3 + 2];
        s_dt = sqrtf(dx * dx + dy * dy + dz * dz);
        const float ex = six - sc3[j * 3], ey = siy - sc3[j * 3 + 1], ez = siz - sc3[j * 3 + 2];
        s_ds = sqrtf(ex * ex + ey * ey + ez * ez);
    };

    auto build_rbfpre = [&]() {
        union { unsigned short u2[4]; uint2 u; } pk;
        {   // pre -> cols 44..63
            const int f0 = 44 + qp0 * 4;
            pk.u2[0] = f2bu(s_prA.x); pk.u2[1] = f2bu(s_prA.y);
            pk.u2[2] = f2bu(s_prA.z); pk.u2[3] = f2bu(s_prA.w);
            *(uint2*)(rbfp + rp0 * 128 + (((f0 >> 3) ^ (rp0 & 7)) << 4) + (f0 & 7) * 2) = pk.u;
            if (tid < 64) {
                const int f1 = 44 + qp1 * 4;
                pk.u2[0] = f2bu(s_prB.x); pk.u2[1] = f2bu(s_prB.y);
                pk.u2[2] = f2bu(s_prB.z); pk.u2[3] = f2bu(s_prB.w);
                *(uint2*)(rbfp + rp1 * 128 + (((f1 >> 3) ^ (rp1 & 7)) << 4) + (f1 & 7) * 2) = pk.u;
            }
        }
        {   // RBF -> cols 0..43
            const int rxr = rr & 7;
            char* rowp = rbfp + rr * 128;
            #pragma unroll
            for (int q = 0; q < 11; q++) {
                const int f = fo + q;
                const float d = (f < 22) ? s_dt : s_ds;
                const int m = (f < 22) ? f : f - 22;
                const float x = (d - (float)m * (20.0f / 21.0f)) * 1.1f;
                *(unsigned short*)(rowp + (((f >> 3) ^ rxr) << 4) + (f & 7) * 2)
                    = f2bu(__expf(-x * x));
            }
        }
    };

    // ---- prologue: tile-0 staging + fused bias1 ----
    float* pshare  = (float*)(smem + 40960);        // H region is free pre-loop
    float* biasLds = (float*)(smem + 40960 + 256);
    if (tid < 64) pshare[tid] = bu2f(((const unsigned short*)p_bf)[i * 64 + tid]);
    stage_glds(0, smem);
    stage_regs(0);
    __syncthreads();   // pshare visible (gl_lds tile0 also drains here)

    float4 bo0, bo1;
    {   // bias1[i][col] = b1[col] + sum_{f<64} p[i][f] * W1b[col][f]
        const int colL = lane & 31;
        const int h = lane >> 5;
        const unsigned short* wrow =
            (const unsigned short*)W1b + (cbase + colL) * 256 + h * 32;
        float acc = 0.f;
        #pragma unroll
        for (int k = 0; k < 4; k++) {
            const v8s w8 = *(const v8s*)(wrow + k * 8);
            #pragma unroll
            for (int e = 0; e < 8; e++)
                acc += pshare[h * 32 + k * 8 + e] * bu2f((unsigned short)w8[e]);
        }
        acc += __shfl_xor(acc, 32);                 // combine halves (f<32 / f>=32)
        biasLds[wv * 32 + colL] = b1[cbase + colL] + acc;   // wave-local region
        bo0 = *(const float4*)&biasLds[wv * 32 + quad * 4];
        bo1 = *(const float4*)&biasLds[wv * 32 + 16 + quad * 4];
    }
    build_rbfpre();
    __syncthreads();   // rbf plane(0) ready; H region now owned by L1 epilogue

    const size_t orow0 = (size_t)i * 512;

    #pragma unroll 1
    for (int s = 0; s < 8; s++) {
        char* slot  = smem + (s & 1) * 16384;
        char* slotN = smem + ((s + 1) & 1) * 16384;
        if (s < 7) { stage_glds((s + 1) * 64, slotN); stage_regs((s + 1) * 64); }

        // ---- Layer 1: K=192, weights in regs ----
        v4f acc[2][4];
        #pragma unroll
        for (int mt = 0; mt < 2; mt++)
            #pragma unroll
            for (int nt = 0; nt < 4; nt++) acc[mt][nt] = (v4f){0.f, 0.f, 0.f, 0.f};

        #pragma unroll
        for (int kt = 0; kt < 6; kt++) {
            // kt 0,1 -> pj plane; 2,3 -> rel plane; 4,5 -> rbf/pre plane
            const char* P = (kt < 2) ? slot : (kt < 4) ? (slot + 8192) : rbfp;
            const int gg = (kt & 1) * 4 + quad;
            const int po = ((gg ^ xr) << 4);
            const v8s t0  = *(const v8s*)(P + (l16     ) * 128 + po);
            const v8s t1  = *(const v8s*)(P + (l16 + 16) * 128 + po);
            const v8s t2  = *(const v8s*)(P + (l16 + 32) * 128 + po);
            const v8s t3v = *(const v8s*)(P + (l16 + 48) * 128 + po);
            acc[0][0] = __builtin_amdgcn_mfma_f32_16x16x32_bf16(w1f[0][kt], t0,  acc[0][0], 0, 0, 0);
            acc[0][1] = __builtin_amdgcn_mfma_f32_16x16x32_bf16(w1f[0][kt], t1,  acc[0][1], 0, 0, 0);
            acc[0][2] = __builtin_amdgcn_mfma_f32_16x16x32_bf16(w1f[0][kt], t2,  acc[0][2], 0, 0, 0);
            acc[0][3] = __builtin_amdgcn_mfma_f32_16x16x32_bf16(w1f[0][kt], t3v, acc[0][3], 0, 0, 0);
            acc[1][0] = __builtin_amdgcn_mfma_f32_16x16x32_bf16(w1f[1][kt], t0,  acc[1][0], 0, 0, 0);
            acc[1][1] = __builtin_amdgcn_mfma_f32_16x16x32_bf16(w1f[1][kt], t1,  acc[1][1], 0, 0, 0);
            acc[1][2] = __builtin_amdgcn_mfma_f32_16x16x32_bf16(w1f[1][kt], t2,  acc[1][2], 0, 0, 0);
            acc[1][3] = __builtin_amdgcn_mfma_f32_16x16x32_bf16(w1f[1][kt], t3v, acc[1][3], 0, 0, 0);
        }

        // ---- H = relu(acc + bias1_i) -> H plane ----
        #pragma unroll
        for (int mt = 0; mt < 2; mt++) {
            const float4 bv = mt ? bo1 : bo0;
            const int col = cbase + mt * 16 + quad * 4;
            const int cch = col >> 3;
            const int boff = (col & 7) * 2;
            #pragma unroll
            for (int nt = 0; nt < 4; nt++) {
                const int row = nt * 16 + l16;
                union { unsigned short u2[4]; uint2 u; } pk;
                pk.u2[0] = f2bu(fmaxf(acc[mt][nt][0] + bv.x, 0.f));
                pk.u2[1] = f2bu(fmaxf(acc[mt][nt][1] + bv.y, 0.f));
                pk.u2[2] = f2bu(fmaxf(acc[mt][nt][2] + bv.z, 0.f));
                pk.u2[3] = f2bu(fmaxf(acc[mt][nt][3] + bv.w, 0.f));
                *(uint2*)(Hb + row * 256 + ((cch ^ (row & 7)) << 4) + boff) = pk.u;
            }
        }
        // MID barrier: H (LDS) complete; L2 phase has NO vmem dependency ->
        // lgkmcnt(0) only. Pre-loads + gl_lds for t+1 stay in flight.
        asm volatile("s_waitcnt lgkmcnt(0)" ::: "memory");
        __builtin_amdgcn_s_barrier();
        __builtin_amdgcn_sched_barrier(0);

        // ---- Layer 2: K=128 from H ----
        v4f acc2[2][4];
        #pragma unroll
        for (int mt = 0; mt < 2; mt++)
            #pragma unroll
            for (int nt = 0; nt < 4; nt++) acc2[mt][nt] = (v4f){0.f, 0.f, 0.f, 0.f};

        #pragma unroll
        for (int kt = 0; kt < 4; kt++) {
            const int g = kt * 4 + quad;
            const int po = ((g ^ xr) << 4);
            const v8s t0  = *(const v8s*)(Hb + (l16     ) * 256 + po);
            const v8s t1  = *(const v8s*)(Hb + (l16 + 16) * 256 + po);
            const v8s t2  = *(const v8s*)(Hb + (l16 + 32) * 256 + po);
            const v8s t3v = *(const v8s*)(Hb + (l16 + 48) * 256 + po);
            acc2[0][0] = __builtin_amdgcn_mfma_f32_16x16x32_bf16(w2f[0][kt], t0,  acc2[0][0], 0, 0, 0);
            acc2[0][1] = __builtin_amdgcn_mfma_f32_16x16x32_bf16(w2f[0][kt], t1,  acc2[0][1], 0, 0, 0);
            acc2[0][2] = __builtin_amdgcn_mfma_f32_16x16x32_bf16(w2f[0][kt], t2,  acc2[0][2], 0, 0, 0);
            acc2[0][3] = __builtin_amdgcn_mfma_f32_16x16x32_bf16(w2f[0][kt], t3v, acc2[0][3], 0, 0, 0);
            acc2[1][0] = __builtin_amdgcn_mfma_f32_16x16x32_bf16(w2f[1][kt], t0,  acc2[1][0], 0, 0, 0);
            acc2[1][1] = __builtin_amdgcn_mfma_f32_16x16x32_bf16(w2f[1][kt], t1,  acc2[1][1], 0, 0, 0);
            acc2[1][2] = __builtin_amdgcn_mfma_f32_16x16x32_bf16(w2f[1][kt], t2,  acc2[1][2], 0, 0, 0);
            acc2[1][3] = __builtin_amdgcn_mfma_f32_16x16x32_bf16(w2f[1][kt], t3v, acc2[1][3], 0, 0, 0);
        }

        // rbf/pre plane for t+1: only L1 reads it, and all L1 reads finished
        // at the mid-barrier -> safe to overwrite here (single-buffered).
        // The implicit vmcnt wait on s_pr*/s_dt here also retires the older
        // gl_lds ops (in-order FIFO) -> slotN guaranteed ready by END.
        if (s < 7) build_rbfpre();

        // ---- epilogue: +b2, plain float4 stores ----
        #pragma unroll
        for (int mt = 0; mt < 2; mt++) {
            const float4 bv = mt ? bz1 : bz0;
            const int col = cbase + mt * 16 + quad * 4;
            #pragma unroll
            for (int nt = 0; nt < 4; nt++) {
                const size_t row = orow0 + s * 64 + nt * 16 + l16;
                float4 o;
                o.x = acc2[mt][nt][0] + bv.x;
                o.y = acc2[mt][nt][1] + bv.y;
                o.z = acc2[mt][nt][2] + bv.z;
                o.w = acc2[mt][nt][3] + bv.w;
                *(float4*)&out[row * 128 + col] = o;
            }
        }

        // END barrier: rbf(t+1) LDS writes visible (lgkm 0); allow the 8
        // epilogue stores to remain in flight (vmcnt 8). gl_lds(t+1) already
        // retired above.
        asm volatile("s_waitcnt vmcnt(8) lgkmcnt(0)" ::: "memory");
        __builtin_amdgcn_s_barrier();
        __builtin_amdgcn_sched_barrier(0);
    }
}

// ---------------------------------------------------------------------------
extern "C" void kernel_launch(void* const* d_in, const int* in_sizes, int n_in,
                              void* d_out, int out_size, void* d_ws, size_t ws_size,
                              hipStream_t stream) {
    const float* s    = (const float*)d_in[0];
    const float* t3   = (const float*)d_in[1];
    const float* sc3  = (const float*)d_in[2];
    const float* pre  = (const float*)d_in[3];
    // d_in[4] = p_mask (all-ones, never applied in reference math)
    const float* W_sp = (const float*)d_in[5];
    const float* b_sp = (const float*)d_in[6];
    const float* W_rp = (const float*)d_in[7];
    const float* b_rp = (const float*)d_in[8];
    const float* W1   = (const float*)d_in[9];
    const float* b1   = (const float*)d_in[10];
    const float* W2   = (const float*)d_in[11];
    const float* b2   = (const float*)d_in[12];
    float* out = (float*)d_out;

    char* ws = (char*)d_ws;
    __hip_bfloat16* p_bf = (__hip_bfloat16*)(ws);                   // 64 KiB @0
    __hip_bfloat16* relT = (__hip_bfloat16*)(ws + 65536);           // 128 KiB
    __hip_bfloat16* W1b  = (__hip_bfloat16*)(ws + 196608);          // 64 KiB
    __hip_bfloat16* W2b  = (__hip_bfloat16*)(ws + 262144);          // 32 KiB

    precompute_kernel<<<344, 256, 0, stream>>>(s, W_sp, b_sp, W_rp, b_rp, W1, W2,
                                               p_bf, relT, W1b, W2b);
    edge_main<<<512, 256, 0, stream>>>(t3, sc3, pre, b1, b2,
                                       p_bf, relT, W1b, W2b, out);
}